// Round 1
// baseline (388.810 us; speedup 1.0000x reference)
//
#include <hip/hip_runtime.h>

#define NCELLS 4096
#define CPB 2
#define NTHREADS 320

struct FBuf {
  float h2[CPB][288];
  float h3[CPB][256];
  float logits[CPB][4];
};

union __align__(16) SMemU {
  float cell[CPB][3 * 48 * 48];   // 13824 floats, phases A/B only
  FBuf f;                         // phases C+ (cell is dead then)
};

__global__ __launch_bounds__(NTHREADS)
void fused_kernel(const float* __restrict__ x,
                  const float* __restrict__ w1, const float* __restrict__ b1,
                  const float* __restrict__ w2, const float* __restrict__ b2,
                  const float* __restrict__ fw1, const float* __restrict__ fb1,
                  const float* __restrict__ fw2, const float* __restrict__ fb2,
                  float* __restrict__ out)
{
  __shared__ SMemU sm;
  __shared__ __align__(16) float s_h1[CPB][16][12][16]; // col-padded: logical x stored at x+1

  const int t = threadIdx.x;
  const int n0 = blockIdx.x * CPB;       // first cell id of this block
  const int b = n0 >> 6;                 // batch (blocks never straddle a batch: 64/CPB integral)

  // ---- Phase A: stage 2 cells into LDS (float4, coalesced rows) + zero h1 ----
  {
    const float4* x4 = (const float4*)x;
    float4* c4 = (float4*)sm.cell;
    for (int q = t; q < CPB * 1728; q += NTHREADS) {   // per cell: 3*48*12 quads
      int cell = q / 1728;
      int r = q - cell * 1728;
      int c = r / 576;
      int r2 = r - c * 576;
      int i = r2 / 12;
      int jq = r2 - i * 12;
      int g = (n0 + cell) & 63;
      int gx = g >> 3, gy = g & 7;
      c4[q] = x4[(size_t)b * 110592 + c * 36864 + (gx * 48 + i) * 96 + gy * 12 + jq];
    }
    float* h1f = &s_h1[0][0][0][0];
    for (int i = t; i < CPB * 16 * 12 * 16; i += NTHREADS) h1f[i] = 0.f;
  }
  __syncthreads();

  // ---- Phase B: conv1 8x8 s4 p2 + ReLU -> h1[16][12][12] ----
  // thread = one spatial output position, 16 oc accumulators in registers.
  // Weight indices are wave-uniform (loop counters only) -> s_load / SGPR operand.
  if (t < CPB * 144) {
    int cell = t / 144;
    int p = t - cell * 144;
    int oy = p / 12, ox = p - oy * 12;
    const float* cp = sm.cell[cell];
    float acc[16];
#pragma unroll
    for (int oc = 0; oc < 16; ++oc) acc[oc] = b1[oc];
    int iy0 = 4 * oy - 2, ix0 = 4 * ox - 2;
    for (int c = 0; c < 3; ++c) {
      for (int ky = 0; ky < 8; ++ky) {
        int iy = iy0 + ky;
        bool rok = ((unsigned)iy < 48u);
        int rbase = c * 2304 + (rok ? iy * 48 : 0);
        float cv[8];
#pragma unroll
        for (int kx = 0; kx < 8; ++kx) {
          int ix = ix0 + kx;
          bool ok = rok & ((unsigned)ix < 48u);
          int off = rbase + (ok ? ix : 0);      // always-valid LDS address
          float v = cp[off];
          cv[kx] = ok ? v : 0.f;
        }
        const float* wp = w1 + c * 64 + ky * 8; // uniform base
#pragma unroll
        for (int kx = 0; kx < 8; ++kx) {
#pragma unroll
          for (int oc = 0; oc < 16; ++oc)
            acc[oc] = fmaf(cv[kx], wp[oc * 192 + kx], acc[oc]);
        }
      }
    }
#pragma unroll
    for (int oc = 0; oc < 16; ++oc)
      s_h1[cell][oc][oy][ox + 1] = fmaxf(acc[oc], 0.f);
  }
  __syncthreads();

  // ---- Phase C: conv2 4x4 s4 p1 + ReLU -> h2[32*3*3] (into union; cell is dead) ----
  for (int o = t; o < CPB * 288; o += NTHREADS) {
    int cell = o / 288;
    int r = o - cell * 288;
    int oc = r / 9;
    int pr = r - oc * 9;
    int oy = pr / 3, ox = pr - oy * 3;
    float acc = b2[oc];
    const float* wp = w2 + oc * 256;
    int iy0 = 4 * oy - 1;
#pragma unroll
    for (int ky = 0; ky < 4; ++ky) {
      int iy = iy0 + ky;
      if ((unsigned)iy < 12u) {
        for (int ci = 0; ci < 16; ++ci) {
          // logical ix = 4*ox-1+kx -> physical col 4*ox+kx, 16B-aligned b128
          const float4 hv = *(const float4*)&s_h1[cell][ci][iy][4 * ox];
          const float* wr = wp + ci * 16 + ky * 4;
          acc = fmaf(hv.x, wr[0], acc);
          acc = fmaf(hv.y, wr[1], acc);
          acc = fmaf(hv.z, wr[2], acc);
          acc = fmaf(hv.w, wr[3], acc);
        }
      }
    }
    sm.f.h2[cell][r] = fmaxf(acc, 0.f);
  }
  __syncthreads();

  // ---- Phase D: fc1 288->256 + ReLU (one neuron x 2 cells per thread) ----
  if (t < 256) {
    float a0 = fb1[t];
    float a1 = a0;
    const float* wr = fw1 + t * 288;
    const float* h0 = sm.f.h2[0];
    const float* h1p = sm.f.h2[1];
    for (int k = 0; k < 288; k += 4) {
      float4 w4 = *(const float4*)(wr + k);
      float4 v0 = *(const float4*)(h0 + k);
      float4 v1 = *(const float4*)(h1p + k);
      a0 = fmaf(v0.x, w4.x, a0); a0 = fmaf(v0.y, w4.y, a0);
      a0 = fmaf(v0.z, w4.z, a0); a0 = fmaf(v0.w, w4.w, a0);
      a1 = fmaf(v1.x, w4.x, a1); a1 = fmaf(v1.y, w4.y, a1);
      a1 = fmaf(v1.z, w4.z, a1); a1 = fmaf(v1.w, w4.w, a1);
    }
    sm.f.h3[0][t] = fmaxf(a0, 0.f);
    sm.f.h3[1][t] = fmaxf(a1, 0.f);
  }
  __syncthreads();

  // ---- Phase E: fc2 256->4 (8 units of 32 lanes, shuffle reduce) ----
  if (t < 256) {
    int unit = t >> 5;            // 0..7 = (cell, j)
    int l = t & 31;
    int cell = unit >> 2, j = unit & 3;
    const float* h3 = sm.f.h3[cell];
    const float* wj = fw2 + j * 256;
    float p = 0.f;
    for (int k = l; k < 256; k += 32) p = fmaf(h3[k], wj[k], p);
#pragma unroll
    for (int off = 16; off >= 1; off >>= 1) p += __shfl_xor(p, off, 32);
    if (l == 0) sm.f.logits[cell][j] = p + fb2[j];
  }
  __syncthreads();

  // ---- Phase F: softmax + store (3 of 4 probs) ----
  if (t < CPB) {
    float l0 = sm.f.logits[t][0], l1 = sm.f.logits[t][1],
          l2 = sm.f.logits[t][2], l3 = sm.f.logits[t][3];
    float m = fmaxf(fmaxf(l0, l1), fmaxf(l2, l3));
    float e0 = __expf(l0 - m), e1 = __expf(l1 - m),
          e2 = __expf(l2 - m), e3 = __expf(l3 - m);
    float inv = 1.f / (e0 + e1 + e2 + e3);
    int n = n0 + t;
    out[n] = e0 * inv;
    out[NCELLS + n] = e1 * inv;
    out[2 * NCELLS + n] = e2 * inv;
  }
}

extern "C" void kernel_launch(void* const* d_in, const int* in_sizes, int n_in,
                              void* d_out, int out_size, void* d_ws, size_t ws_size,
                              hipStream_t stream) {
  const float* x   = (const float*)d_in[0];
  const float* w1  = (const float*)d_in[1];
  const float* b1  = (const float*)d_in[2];
  const float* w2  = (const float*)d_in[3];
  const float* b2  = (const float*)d_in[4];
  const float* fw1 = (const float*)d_in[5];
  const float* fb1 = (const float*)d_in[6];
  const float* fw2 = (const float*)d_in[7];
  const float* fb2 = (const float*)d_in[8];
  float* out = (float*)d_out;

  hipLaunchKernelGGL(fused_kernel, dim3(NCELLS / CPB), dim3(NTHREADS), 0, stream,
                     x, w1, b1, w2, b2, fw1, fb1, fw2, fb2, out);
}

// Round 2
// 207.515 us; speedup vs baseline: 1.8736x; 1.8736x over previous
//
#include <hip/hip_runtime.h>

#define NCELLS 4096
#define CPB 4            // cells per block, processed sequentially
#define NT 192           // 3 waves: lane = (oc 0..15, oy 0..11)

__global__ __launch_bounds__(NT, 3)
void fused_kernel(const float* __restrict__ x,
                  const float* __restrict__ w1, const float* __restrict__ b1,
                  const float* __restrict__ w2, const float* __restrict__ b2,
                  const float* __restrict__ fw1, const float* __restrict__ fb1,
                  const float* __restrict__ fw2, const float* __restrict__ fb2,
                  float* __restrict__ out)
{
  __shared__ __align__(16) float w1t[192 * 16];      // [kidx=(c*8+ky)*8+kx][oc] 12.3 KB
  __shared__ __align__(16) float h1[16][12][20];     // phys col = logical ix + 1; 15.4 KB
  __shared__ __align__(16) float h2s[CPB][288];      // 4.6 KB
  __shared__ __align__(16) float h3s[CPB][256];      // 4.1 KB
  __shared__ float logits_s[CPB][4];

  const int t = threadIdx.x;
  const int oc = t & 15;
  const int oy = t >> 4;           // 0..11

  // ---- stage w1 transposed: w1t[kidx*16 + oc] = w1[oc*192 + kidx] ----
  for (int d = t; d < 3072; d += NT) {
    int o = d & 15, kidx = d >> 4;
    w1t[d] = w1[o * 192 + kidx];
  }
  const float bias1 = b1[oc];
  __syncthreads();

  const int cell0 = blockIdx.x * CPB;

  for (int cl = 0; cl < CPB; ++cl) {
    const int cell = cell0 + cl;
    const int b = cell >> 6;
    const int g = cell & 63;
    const int gx = g >> 3, gy = g & 7;
    const float* xb = x + (size_t)b * 442368 + (size_t)(gx * 48) * 384 + gy * 48;

    // ---- conv1 8x8 s4 p2 + ReLU: thread = (oc, oy), 12 ox accumulators ----
    float acc[12];
#pragma unroll
    for (int i = 0; i < 12; ++i) acc[i] = bias1;

    for (int c = 0; c < 3; ++c) {
      for (int ky = 0; ky < 8; ++ky) {
        int iy = 4 * oy - 2 + ky;
        if ((unsigned)iy < 48u) {
          const float4* row = (const float4*)(xb + c * 147456 + (size_t)iy * 384);
          const float* wl = &w1t[(c * 8 + ky) * 128 + oc];
          float w[8];
#pragma unroll
          for (int kx = 0; kx < 8; ++kx) w[kx] = wl[kx * 16];
          // sliding 3-chunk window: output ox uses ix 4ox-2 .. 4ox+5
          float4 A = make_float4(0.f, 0.f, 0.f, 0.f);
          float4 Bv = row[0];
#pragma unroll
          for (int ox = 0; ox < 12; ++ox) {
            float4 Cv = (ox < 11) ? row[ox + 1] : make_float4(0.f, 0.f, 0.f, 0.f);
            acc[ox] = fmaf(A.z,  w[0], acc[ox]);
            acc[ox] = fmaf(A.w,  w[1], acc[ox]);
            acc[ox] = fmaf(Bv.x, w[2], acc[ox]);
            acc[ox] = fmaf(Bv.y, w[3], acc[ox]);
            acc[ox] = fmaf(Bv.z, w[4], acc[ox]);
            acc[ox] = fmaf(Bv.w, w[5], acc[ox]);
            acc[ox] = fmaf(Cv.x, w[6], acc[ox]);
            acc[ox] = fmaf(Cv.y, w[7], acc[ox]);
            A = Bv; Bv = Cv;
          }
        }
      }
    }
    // write h1 row (phys cols 1..12), zero the left-pad col 0
    h1[oc][oy][0] = 0.f;
#pragma unroll
    for (int ox = 0; ox < 12; ++ox) h1[oc][oy][ox + 1] = fmaxf(acc[ox], 0.f);
    __syncthreads();

    // ---- conv2 4x4 s4 p1 + ReLU: 144 threads = (ocp 0..15, p 0..8), 2 oc each ----
    if (t < 144) {
      int ocp = t / 9, p = t - ocp * 9;
      int o2y = p / 3, o2x = p - o2y * 3;
      int oc0 = ocp * 2;
      float a0 = b2[oc0], a1 = b2[oc0 + 1];
#pragma unroll
      for (int ky = 0; ky < 4; ++ky) {
        int iy = 4 * o2y - 1 + ky;
        if ((unsigned)iy < 12u) {
          for (int ci = 0; ci < 16; ++ci) {
            float4 h = *(const float4*)&h1[ci][iy][4 * o2x];  // logical ix = 4*o2x-1 .. +2
            const float* wr = w2 + (oc0 * 16 + ci) * 16 + ky * 4;
            float4 w0 = *(const float4*)(wr);
            float4 w1v = *(const float4*)(wr + 256);
            a0 = fmaf(h.x, w0.x, a0);  a0 = fmaf(h.y, w0.y, a0);
            a0 = fmaf(h.z, w0.z, a0);  a0 = fmaf(h.w, w0.w, a0);
            a1 = fmaf(h.x, w1v.x, a1); a1 = fmaf(h.y, w1v.y, a1);
            a1 = fmaf(h.z, w1v.z, a1); a1 = fmaf(h.w, w1v.w, a1);
          }
        }
      }
      h2s[cl][oc0 * 9 + p] = fmaxf(a0, 0.f);
      h2s[cl][(oc0 + 1) * 9 + p] = fmaxf(a1, 0.f);
    }
    __syncthreads();   // also protects h1 for next cell
  }

  // ---- fc1 288->256 + ReLU, all CPB cells at once ----
  {
    const float4* h0 = (const float4*)h2s[0];
    const float4* h1p = (const float4*)h2s[1];
    const float4* h2p = (const float4*)h2s[2];
    const float4* h3p = (const float4*)h2s[3];
    for (int pass = 0; pass < 2; ++pass) {
      int n = (pass == 0) ? t : NT + t;
      if (n < 256) {
        float a0 = fb1[n], a1 = a0, a2 = a0, a3 = a0;
        const float4* wr = (const float4*)(fw1 + n * 288);
        for (int k4 = 0; k4 < 72; ++k4) {
          float4 w4 = wr[k4];
          float4 v0 = h0[k4], v1 = h1p[k4], v2 = h2p[k4], v3 = h3p[k4];
          a0 = fmaf(v0.x, w4.x, a0); a0 = fmaf(v0.y, w4.y, a0);
          a0 = fmaf(v0.z, w4.z, a0); a0 = fmaf(v0.w, w4.w, a0);
          a1 = fmaf(v1.x, w4.x, a1); a1 = fmaf(v1.y, w4.y, a1);
          a1 = fmaf(v1.z, w4.z, a1); a1 = fmaf(v1.w, w4.w, a1);
          a2 = fmaf(v2.x, w4.x, a2); a2 = fmaf(v2.y, w4.y, a2);
          a2 = fmaf(v2.z, w4.z, a2); a2 = fmaf(v2.w, w4.w, a2);
          a3 = fmaf(v3.x, w4.x, a3); a3 = fmaf(v3.y, w4.y, a3);
          a3 = fmaf(v3.z, w4.z, a3); a3 = fmaf(v3.w, w4.w, a3);
        }
        h3s[0][n] = fmaxf(a0, 0.f);
        h3s[1][n] = fmaxf(a1, 0.f);
        h3s[2][n] = fmaxf(a2, 0.f);
        h3s[3][n] = fmaxf(a3, 0.f);
      }
    }
  }
  __syncthreads();

  // ---- fc2 256->4: 128 threads = 16 units x 8 lanes, shuffle reduce ----
  if (t < 128) {
    int unit = t >> 3, sub = t & 7;
    int cl = unit >> 2, j = unit & 3;
    const float4* wj = (const float4*)(fw2 + j * 256);
    const float4* hp = (const float4*)h3s[cl];
    float p = 0.f;
    for (int k4 = sub; k4 < 64; k4 += 8) {
      float4 w4 = wj[k4], h4 = hp[k4];
      p = fmaf(h4.x, w4.x, p); p = fmaf(h4.y, w4.y, p);
      p = fmaf(h4.z, w4.z, p); p = fmaf(h4.w, w4.w, p);
    }
    p += __shfl_xor(p, 1);
    p += __shfl_xor(p, 2);
    p += __shfl_xor(p, 4);
    if (sub == 0) logits_s[cl][j] = p + fb2[j];
  }
  __syncthreads();

  // ---- softmax + store (3 of 4 probs) ----
  if (t < CPB) {
    float l0 = logits_s[t][0], l1 = logits_s[t][1],
          l2 = logits_s[t][2], l3 = logits_s[t][3];
    float m = fmaxf(fmaxf(l0, l1), fmaxf(l2, l3));
    float e0 = __expf(l0 - m), e1 = __expf(l1 - m),
          e2 = __expf(l2 - m), e3 = __expf(l3 - m);
    float inv = 1.f / (e0 + e1 + e2 + e3);
    int n = cell0 + t;
    out[n] = e0 * inv;
    out[NCELLS + n] = e1 * inv;
    out[2 * NCELLS + n] = e2 * inv;
  }
}

extern "C" void kernel_launch(void* const* d_in, const int* in_sizes, int n_in,
                              void* d_out, int out_size, void* d_ws, size_t ws_size,
                              hipStream_t stream) {
  const float* x   = (const float*)d_in[0];
  const float* w1  = (const float*)d_in[1];
  const float* b1  = (const float*)d_in[2];
  const float* w2  = (const float*)d_in[3];
  const float* b2  = (const float*)d_in[4];
  const float* fw1 = (const float*)d_in[5];
  const float* fb1 = (const float*)d_in[6];
  const float* fw2 = (const float*)d_in[7];
  const float* fb2 = (const float*)d_in[8];
  float* out = (float*)d_out;

  hipLaunchKernelGGL(fused_kernel, dim3(NCELLS / CPB), dim3(NT), 0, stream,
                     x, w1, b1, w2, b2, fw1, fb1, fw2, fb2, out);
}

// Round 3
// 82.124 us; speedup vs baseline: 4.7344x; 2.5268x over previous
//
#include <hip/hip_runtime.h>

typedef float f32x4 __attribute__((ext_vector_type(4)));
typedef short s16x8 __attribute__((ext_vector_type(8)));

#define NT 256
#define CPBLK 16
#define ROUNDS 4

#define CB_ROW 56
#define CB_PLANE (52 * CB_ROW)   // 2912
#define CB_CELL (3 * CB_PLANE)   // 8736
#define A2_STR 264
#define W2_STR 264
#define H2_STR 296
#define H3_STR 260

__device__ __forceinline__ ushort f2bf(float f) {
  unsigned u = __float_as_uint(f);
  unsigned r = (u + 0x7fffu + ((u >> 16) & 1u)) >> 16;
  return (ushort)r;
}

__global__ void prep_kernel(const float* __restrict__ fw1, ushort* __restrict__ fw1b) {
  int i = blockIdx.x * 256 + threadIdx.x;      // 288 * 256 = 73728 exact
  fw1b[i] = f2bf(fw1[i]);
}

__global__ __launch_bounds__(NT)
void fused_kernel(const float* __restrict__ x,
                  const float* __restrict__ w1, const float* __restrict__ b1,
                  const float* __restrict__ w2, const float* __restrict__ b2,
                  const ushort* __restrict__ fw1b, const float* __restrict__ fb1,
                  const float* __restrict__ fw2, const float* __restrict__ fb2,
                  float* __restrict__ out)
{
  __shared__ __align__(16) ushort cb[4 * CB_CELL];   // 69888 B padded bf16 cells
  __shared__ __align__(16) ushort A2[48 * A2_STR];   // 25344 B conv2 im2col
  __shared__ __align__(16) ushort w2t[32 * W2_STR];  // 16896 B
  __shared__ __align__(16) ushort h2[16 * H2_STR];   // 9472 B
  __shared__ __align__(16) float  h3[16 * H3_STR];   // 16640 B
  __shared__ float ls[16][4];

  const int t = threadIdx.x;
  const int w = t >> 6;
  const int lane = t & 63;
  const int r16 = lane & 15;
  const int g = lane >> 4;

  // one-time zero: cell borders + A2 pad slots stay 0 for the whole kernel
  {
    uint* p1 = (uint*)cb;
    for (int i = t; i < (4 * CB_CELL) / 2; i += NT) p1[i] = 0u;
    uint* p2 = (uint*)A2;
    for (int i = t; i < (48 * A2_STR) / 2; i += NT) p2[i] = 0u;
  }
  // stage w2 -> bf16 LDS [oc2][264]
  for (int i = t; i < 32 * 256; i += NT) {
    int oc = i >> 8, k = i & 255;
    w2t[oc * W2_STR + k] = f2bf(w2[i]);
  }
  // preload conv1 B-fragments: lane holds w1[oc=r16][k = 32s + 8g .. +7]
  s16x8 b1f[6];
#pragma unroll
  for (int s = 0; s < 6; ++s) {
    const float* p = w1 + r16 * 192 + s * 32 + g * 8;
    float4 lo = *(const float4*)p;
    float4 hi = *(const float4*)(p + 4);
    s16x8 v;
    v[0] = (short)f2bf(lo.x); v[1] = (short)f2bf(lo.y);
    v[2] = (short)f2bf(lo.z); v[3] = (short)f2bf(lo.w);
    v[4] = (short)f2bf(hi.x); v[5] = (short)f2bf(hi.y);
    v[6] = (short)f2bf(hi.z); v[7] = (short)f2bf(hi.w);
    b1f[s] = v;
  }
  const float b1v = b1[r16];
  const float b2v0 = b2[r16], b2v1 = b2[16 + r16];

  // per-lane conv1 A-row offsets (elems within one channel plane)
  int rowA[9];
#pragma unroll
  for (int mt = 0; mt < 9; ++mt) {
    int m = mt * 16 + r16;
    int oy = m / 12, ox = m - 12 * oy;
    rowA[mt] = oy * (4 * CB_ROW) + 4 * ox;
  }
  __syncthreads();

  const int cell00 = blockIdx.x * CPBLK;
  const float4* x4 = (const float4*)x;

  for (int rnd = 0; rnd < ROUNDS; ++rnd) {
    // ---- stage 4 cells fp32 -> bf16 LDS (27*256 = 6912 tasks exact) ----
    for (int i = 0; i < 27; ++i) {
      int q = i * NT + t;
      int cir = q / 1728;
      int rem = q - cir * 1728;
      int c = rem / 576;
      int rem2 = rem - c * 576;
      int y = rem2 / 12;
      int quad = rem2 - y * 12;
      int n = cell00 + rnd * 4 + cir;
      int b = n >> 6, gcell = n & 63;
      int gx = gcell >> 3, gy = gcell & 7;
      float4 v = x4[(size_t)b * 110592 + c * 36864 + (gx * 48 + y) * 96 + gy * 12 + quad];
      int e = cir * CB_CELL + c * CB_PLANE + (y + 2) * CB_ROW + 2 + quad * 4;
      *(uint*)&cb[e]     = (uint)f2bf(v.x) | ((uint)f2bf(v.y) << 16);
      *(uint*)&cb[e + 2] = (uint)f2bf(v.z) | ((uint)f2bf(v.w) << 16);
    }
    __syncthreads();

    // ---- conv1 MFMA: wave w owns cell w. M=144=9x16, N=16, K=192 ----
    f32x4 acc[9];
#pragma unroll
    for (int mt = 0; mt < 9; ++mt) acc[mt] = (f32x4){0.f, 0.f, 0.f, 0.f};
#pragma unroll
    for (int s = 0; s < 6; ++s) {
      int c = s >> 1, kyb = (s & 1) * 4;
      int base = w * CB_CELL + c * CB_PLANE + (kyb + g) * CB_ROW;
#pragma unroll
      for (int mt = 0; mt < 9; ++mt) {
        int e = base + rowA[mt];
        s16x8 a;
        ((uint2*)&a)[0] = *(const uint2*)&cb[e];
        ((uint2*)&a)[1] = *(const uint2*)&cb[e + 4];
        acc[mt] = __builtin_amdgcn_mfma_f32_16x16x32_bf16(a, b1f[s], acc[mt], 0, 0, 0);
      }
    }
    // epilogue: bias+relu, scatter into conv2 im2col A2 (disjoint patches)
#pragma unroll
    for (int mt = 0; mt < 9; ++mt) {
#pragma unroll
      for (int rr = 0; rr < 4; ++rr) {
        int m = mt * 16 + g * 4 + rr;
        int oy = m / 12, ox = m - 12 * oy;
        if (oy < 11 && ox < 11) {
          float v = fmaxf(acc[mt][rr] + b1v, 0.f);
          int p2y = (oy + 1) >> 2, k2y = (oy + 1) & 3;
          int p2x = (ox + 1) >> 2, k2x = (ox + 1) & 3;
          A2[(w * 9 + p2y * 3 + p2x) * A2_STR + r16 * 16 + k2y * 4 + k2x] = f2bf(v);
        }
      }
    }
    __syncthreads();

    // ---- conv2 MFMA: M=36(pad48), N=32, K=256; 6 tile-pairs over 4 waves ----
    for (int p = w; p < 6; p += 4) {
      int mt2 = p >> 1, nt = p & 1;
      f32x4 a2c = (f32x4){0.f, 0.f, 0.f, 0.f};
#pragma unroll
      for (int s2 = 0; s2 < 8; ++s2) {
        uint4 qa = *(const uint4*)&A2[(mt2 * 16 + r16) * A2_STR + s2 * 32 + g * 8];
        uint4 qb = *(const uint4*)&w2t[(nt * 16 + r16) * W2_STR + s2 * 32 + g * 8];
        a2c = __builtin_amdgcn_mfma_f32_16x16x32_bf16(*(s16x8*)&qa, *(s16x8*)&qb, a2c, 0, 0, 0);
      }
      float bb = (nt == 0) ? b2v0 : b2v1;
#pragma unroll
      for (int rr = 0; rr < 4; ++rr) {
        int m2 = mt2 * 16 + g * 4 + rr;
        if (m2 < 36) {
          int cir = m2 / 9, p2 = m2 - 9 * cir;
          float v = fmaxf(a2c[rr] + bb, 0.f);
          h2[(rnd * 4 + cir) * H2_STR + (nt * 16 + r16) * 9 + p2] = f2bf(v);
        }
      }
    }
    __syncthreads();
  }

  // ---- fc1 MFMA: M=16 cells (full tile), N=256 (wave w -> n-tiles 4w..4w+3), K=288 ----
  {
    s16x8 af[9];
#pragma unroll
    for (int s = 0; s < 9; ++s) {
      uint4 qa = *(const uint4*)&h2[r16 * H2_STR + s * 32 + g * 8];
      af[s] = *(s16x8*)&qa;
    }
    f32x4 facc[4];
#pragma unroll
    for (int i = 0; i < 4; ++i) facc[i] = (f32x4){0.f, 0.f, 0.f, 0.f};
#pragma unroll
    for (int i = 0; i < 4; ++i) {
      int nt = w * 4 + i;
#pragma unroll
      for (int s = 0; s < 9; ++s) {
        uint4 qb = *(const uint4*)(fw1b + (nt * 16 + r16) * 288 + s * 32 + g * 8);
        facc[i] = __builtin_amdgcn_mfma_f32_16x16x32_bf16(af[s], *(s16x8*)&qb, facc[i], 0, 0, 0);
      }
    }
#pragma unroll
    for (int i = 0; i < 4; ++i) {
      int n = (w * 4 + i) * 16 + r16;
      float fb = fb1[n];
#pragma unroll
      for (int rr = 0; rr < 4; ++rr) {
        int cell = g * 4 + rr;
        h3[cell * H3_STR + n] = fmaxf(facc[i][rr] + fb, 0.f);
      }
    }
  }
  __syncthreads();

  // ---- fc2 (fp32 VALU) : 64 units x 4 lanes ----
  {
    int u = t >> 2, sub = t & 3;
    int cell = u >> 2, j = u & 3;
    const float4* hp = (const float4*)&h3[cell * H3_STR + sub * 64];
    const float4* wp = (const float4*)(fw2 + j * 256 + sub * 64);
    float p = 0.f;
#pragma unroll
    for (int i = 0; i < 16; ++i) {
      float4 a = hp[i], b = wp[i];
      p = fmaf(a.x, b.x, p); p = fmaf(a.y, b.y, p);
      p = fmaf(a.z, b.z, p); p = fmaf(a.w, b.w, p);
    }
    p += __shfl_xor(p, 1);
    p += __shfl_xor(p, 2);
    if (sub == 0) ls[cell][j] = p + fb2[j];
  }
  __syncthreads();

  // ---- softmax + store ----
  if (t < CPBLK) {
    float l0 = ls[t][0], l1 = ls[t][1], l2 = ls[t][2], l3 = ls[t][3];
    float m = fmaxf(fmaxf(l0, l1), fmaxf(l2, l3));
    float e0 = __expf(l0 - m), e1 = __expf(l1 - m),
          e2 = __expf(l2 - m), e3 = __expf(l3 - m);
    float inv = 1.f / (e0 + e1 + e2 + e3);
    int n = cell00 + t;
    out[n] = e0 * inv;
    out[4096 + n] = e1 * inv;
    out[8192 + n] = e2 * inv;
  }
}

extern "C" void kernel_launch(void* const* d_in, const int* in_sizes, int n_in,
                              void* d_out, int out_size, void* d_ws, size_t ws_size,
                              hipStream_t stream) {
  const float* x   = (const float*)d_in[0];
  const float* w1  = (const float*)d_in[1];
  const float* b1  = (const float*)d_in[2];
  const float* w2  = (const float*)d_in[3];
  const float* b2  = (const float*)d_in[4];
  const float* fw1 = (const float*)d_in[5];
  const float* fb1 = (const float*)d_in[6];
  const float* fw2 = (const float*)d_in[7];
  const float* fb2 = (const float*)d_in[8];
  float* out = (float*)d_out;
  ushort* fw1b = (ushort*)d_ws;    // 147456 B bf16 copy of fw1

  hipLaunchKernelGGL(prep_kernel, dim3(288), dim3(256), 0, stream, fw1, fw1b);
  hipLaunchKernelGGL(fused_kernel, dim3(4096 / CPBLK), dim3(NT), 0, stream,
                     x, w1, b1, w2, b2, fw1b, fb1, fw2, fb2, out);
}

// Round 4
// 50.855 us; speedup vs baseline: 7.6454x; 1.6149x over previous
//
#include <hip/hip_runtime.h>

typedef float f32x4 __attribute__((ext_vector_type(4)));
typedef short s16x8 __attribute__((ext_vector_type(8)));

#define NT 512

#define CB_ROW 52
#define CB_PLANE 2704          // 52*52
#define CB_CELL 8112           // 3*2704
#define H1_CI 208              // 13*16
#define H1_CELL 3328           // 16*208
#define W2_STR 264
#define H2_STR 296
#define H3_STR 260

__device__ __forceinline__ ushort f2bf(float f) {
  unsigned u = __float_as_uint(f);
  unsigned r = (u + 0x7fffu + ((u >> 16) & 1u)) >> 16;
  return (ushort)r;
}

__device__ __forceinline__ int cellbase4(int n) {   // float4 index of cell n's origin in x
  int b = n >> 6, gg = n & 63;
  return b * 110592 + (gg >> 3) * 4608 + (gg & 7) * 12;
}

__global__ void prep_kernel(const float* __restrict__ fw1, ushort* __restrict__ fw1b) {
  int i = blockIdx.x * 256 + threadIdx.x;            // 288*256 = 73728 exact
  fw1b[i] = f2bf(fw1[i]);
}

__global__ __launch_bounds__(NT, 4)
void fused_kernel(const float* __restrict__ x,
                  const float* __restrict__ w1, const float* __restrict__ b1,
                  const float* __restrict__ w2, const float* __restrict__ b2,
                  const ushort* __restrict__ fw1b, const float* __restrict__ fb1,
                  const float* __restrict__ fw2, const float* __restrict__ fb2,
                  float* __restrict__ out)
{
  __shared__ __align__(16) ushort cb[2 * CB_CELL];    // 32448 B  2 cells [3][52][52] bf16
  __shared__ __align__(16) ushort h1[2 * H1_CELL];    // 13312 B  2 cells [16][13][16] bf16
  __shared__ __align__(16) ushort w2t[32 * W2_STR];   // 16896 B
  __shared__ __align__(16) ushort h2[16 * H2_STR];    // 9472 B  (rows 8..15 stay 0)
  __shared__ __align__(16) float  h3[8 * H3_STR];     // 8320 B
  __shared__ float ls[8][4];                          // total 80576 B -> 2 blocks/CU

  const int t = threadIdx.x;
  const int w = t >> 6;
  const int lane = t & 63;
  const int r16 = lane & 15;
  const int g = lane >> 4;

  // ---- per-thread staging task descriptors (3456 float4 tasks / round) ----
  int cls[7], goff[7], eoff[7];
#pragma unroll
  for (int i = 0; i < 7; ++i) {
    int q = i * NT + t;
    bool valid = q < 3456;
    int qq = valid ? q : 0;
    int cl = qq >= 1728 ? 1 : 0;
    int rem = qq - cl * 1728;
    int c = rem / 576; int r2 = rem - c * 576;
    int y = r2 / 12;   int quad = r2 - y * 12;
    cls[i] = valid ? cl : -1;
    goff[i] = c * 36864 + y * 96 + quad;
    eoff[i] = cl * CB_CELL + c * CB_PLANE + (y + 2) * CB_ROW + 2 + quad * 4;
  }

  const int cell00 = blockIdx.x * 8;
  const float4* x4 = (const float4*)x;

  // ---- prefetch round 0 into registers (overlaps init) ----
  float4 v[7];
  {
    int b0 = cellbase4(cell00), b1_ = cellbase4(cell00 + 1);
#pragma unroll
    for (int i = 0; i < 7; ++i)
      if (cls[i] >= 0) v[i] = x4[(cls[i] ? b1_ : b0) + goff[i]];
  }

  // ---- one-time zero (borders persist across rounds) + w2 stage ----
  for (int i = t; i < CB_CELL; i += NT) ((uint*)cb)[i] = 0u;       // 8112 uints
  for (int i = t; i < H1_CELL; i += NT) ((uint*)h1)[i] = 0u;       // 3328 uints
  for (int i = t; i < 2368; i += NT) ((uint*)h2)[i] = 0u;          // 16*296/2
  for (int i = t; i < 8192; i += NT) {
    int oc = i >> 8, k = i & 255;
    w2t[oc * W2_STR + k] = f2bf(w2[i]);
  }

  // ---- conv1 B-fragments in registers: lane holds w1[oc=r16][k=32s+8g..+7] ----
  s16x8 b1f[6];
#pragma unroll
  for (int s = 0; s < 6; ++s) {
    const float* p = w1 + r16 * 192 + s * 32 + g * 8;
    float4 lo = *(const float4*)p;
    float4 hi = *(const float4*)(p + 4);
    s16x8 vv;
    vv[0] = (short)f2bf(lo.x); vv[1] = (short)f2bf(lo.y);
    vv[2] = (short)f2bf(lo.z); vv[3] = (short)f2bf(lo.w);
    vv[4] = (short)f2bf(hi.x); vv[5] = (short)f2bf(hi.y);
    vv[6] = (short)f2bf(hi.z); vv[7] = (short)f2bf(hi.w);
    b1f[s] = vv;
  }
  const float b1v = b1[r16];
  const float b2v = b2[(w & 1) * 16 + r16];

  // ---- conv1 lane constants: wave w -> cell (w>>2), m-tiles {w&3, +4, +8} ----
  const int mtbase = w & 3;
  const int clA = w >> 2;
  int rowA[3];
#pragma unroll
  for (int ii = 0; ii < 3; ++ii) {
    int mt = mtbase + ii * 4;
    int m = (mt < 9 ? mt : 0) * 16 + r16;
    int oy = m / 12, ox = m - 12 * oy;
    rowA[ii] = oy * 208 + 4 * ox;        // 208 = 4*CB_ROW
  }
  // ---- conv2 lane constants (waves 0..3): unit = (cell w>>1, ntile w&1) ----
  const int pcl = r16 < 9 ? r16 : 8;
  const int p2y = pcl / 3, p2x = pcl - 3 * p2y;
  const int lco = (g >> 1) * H1_CI + (4 * p2y + 2 * (g & 1)) * 16 + 4 * p2x;
  const int cellC = (w >> 1) & 1, ntC = w & 1;

  __syncthreads();

  for (int rnd = 0; rnd < 4; ++rnd) {
    // ---- write staged cells to LDS (bf16) ----
#pragma unroll
    for (int i = 0; i < 7; ++i)
      if (cls[i] >= 0) {
        float4 q = v[i]; int e = eoff[i];
        *(uint*)&cb[e]     = (uint)f2bf(q.x) | ((uint)f2bf(q.y) << 16);
        *(uint*)&cb[e + 2] = (uint)f2bf(q.z) | ((uint)f2bf(q.w) << 16);
      }
    __syncthreads();

    // ---- conv1 MFMA: M=144 (9 mt-tiles over 4 waves), N=16, K=192 ----
    f32x4 acc[3];
#pragma unroll
    for (int ii = 0; ii < 3; ++ii) acc[ii] = (f32x4){0.f, 0.f, 0.f, 0.f};
    const ushort* cbc = cb + clA * CB_CELL;
#pragma unroll
    for (int s = 0; s < 6; ++s) {
      int sbase = (s >> 1) * CB_PLANE + ((s & 1) * 4 + g) * CB_ROW;
#pragma unroll
      for (int ii = 0; ii < 3; ++ii) {
        if (mtbase + ii * 4 < 9) {
          int e = sbase + rowA[ii];
          s16x8 a;
          ((uint2*)&a)[0] = *(const uint2*)&cbc[e];
          ((uint2*)&a)[1] = *(const uint2*)&cbc[e + 4];
          acc[ii] = __builtin_amdgcn_mfma_f32_16x16x32_bf16(a, b1f[s], acc[ii], 0, 0, 0);
        }
      }
    }
    // epilogue: bias+relu -> h1 (phys +1 border offsets)
    {
      ushort* h1c = h1 + clA * H1_CELL;
#pragma unroll
      for (int ii = 0; ii < 3; ++ii) {
        int mt = mtbase + ii * 4;
        if (mt < 9) {
#pragma unroll
          for (int rr = 0; rr < 4; ++rr) {
            int m = mt * 16 + g * 4 + rr;
            int oy = m / 12, ox = m - 12 * oy;
            float val = fmaxf(acc[ii][rr] + b1v, 0.f);
            h1c[r16 * H1_CI + (oy + 1) * 16 + (ox + 1)] = f2bf(val);
          }
        }
      }
    }

    // ---- prefetch next round's cells into registers (hides HBM under conv2) ----
    if (rnd < 3) {
      int n0 = cell00 + (rnd + 1) * 2;
      int b0 = cellbase4(n0), b1_ = cellbase4(n0 + 1);
#pragma unroll
      for (int i = 0; i < 7; ++i)
        if (cls[i] >= 0) v[i] = x4[(cls[i] ? b1_ : b0) + goff[i]];
    }
    __syncthreads();

    // ---- conv2 MFMA: per cell M=9(pad16), N=32, K=256; waves 0..3 ----
    if (w < 4) {
      const ushort* h1cc = h1 + cellC * H1_CELL;
      f32x4 a2 = (f32x4){0.f, 0.f, 0.f, 0.f};
#pragma unroll
      for (int s2 = 0; s2 < 8; ++s2) {
        int off = s2 * 416 + lco;       // 416 = 2*H1_CI
        s16x8 a;
        ((uint2*)&a)[0] = *(const uint2*)&h1cc[off];
        ((uint2*)&a)[1] = *(const uint2*)&h1cc[off + 16];
        uint4 qb = *(const uint4*)&w2t[(ntC * 16 + r16) * W2_STR + s2 * 32 + g * 8];
        a2 = __builtin_amdgcn_mfma_f32_16x16x32_bf16(a, *(s16x8*)&qb, a2, 0, 0, 0);
      }
#pragma unroll
      for (int rr = 0; rr < 4; ++rr) {
        int m2 = g * 4 + rr;
        if (m2 < 9) {
          float val = fmaxf(a2[rr] + b2v, 0.f);
          h2[(rnd * 2 + cellC) * H2_STR + (ntC * 16 + r16) * 9 + m2] = f2bf(val);
        }
      }
    }
    // no end barrier needed: next write-cb touches cb only (conv1 readers all
    // passed the mid barrier); next conv1's h1 writes are after the next mid barrier.
  }
  __syncthreads();

  // ---- fc1 MFMA: M=8 cells (pad16), N=256 (wave w -> n-tiles 2w, 2w+1), K=288 ----
  {
    s16x8 af[9];
#pragma unroll
    for (int s = 0; s < 9; ++s) {
      uint4 qa = *(const uint4*)&h2[r16 * H2_STR + s * 32 + g * 8];
      af[s] = *(s16x8*)&qa;
    }
    f32x4 fa0 = (f32x4){0.f, 0.f, 0.f, 0.f};
    f32x4 fa1 = (f32x4){0.f, 0.f, 0.f, 0.f};
#pragma unroll
    for (int s = 0; s < 9; ++s) {
      uint4 q0 = *(const uint4*)(fw1b + ((2 * w) * 16 + r16) * 288 + s * 32 + g * 8);
      fa0 = __builtin_amdgcn_mfma_f32_16x16x32_bf16(af[s], *(s16x8*)&q0, fa0, 0, 0, 0);
      uint4 q1 = *(const uint4*)(fw1b + ((2 * w + 1) * 16 + r16) * 288 + s * 32 + g * 8);
      fa1 = __builtin_amdgcn_mfma_f32_16x16x32_bf16(af[s], *(s16x8*)&q1, fa1, 0, 0, 0);
    }
#pragma unroll
    for (int i = 0; i < 2; ++i) {
      f32x4 fa = i ? fa1 : fa0;
      int n = (2 * w + i) * 16 + r16;
      float fb = fb1[n];
#pragma unroll
      for (int rr = 0; rr < 4; ++rr) {
        int cell = g * 4 + rr;
        if (cell < 8) h3[cell * H3_STR + n] = fmaxf(fa[rr] + fb, 0.f);
      }
    }
  }
  __syncthreads();

  // ---- fc2: 32 units (8 cells x 4 logits) x 16 lanes ----
  {
    int u = t >> 4, sub = t & 15;
    int cell = u >> 2, j = u & 3;
    const float4* hp = (const float4*)&h3[cell * H3_STR];
    const float4* wp = (const float4*)(fw2 + j * 256);
    float p = 0.f;
#pragma unroll
    for (int i = 0; i < 4; ++i) {
      int k4 = sub + i * 16;
      float4 a = hp[k4], b = wp[k4];
      p = fmaf(a.x, b.x, p); p = fmaf(a.y, b.y, p);
      p = fmaf(a.z, b.z, p); p = fmaf(a.w, b.w, p);
    }
    p += __shfl_xor(p, 1);
    p += __shfl_xor(p, 2);
    p += __shfl_xor(p, 4);
    p += __shfl_xor(p, 8);
    if (sub == 0) ls[cell][j] = p + fb2[j];
  }
  __syncthreads();

  // ---- softmax + store ----
  if (t < 8) {
    float l0 = ls[t][0], l1 = ls[t][1], l2 = ls[t][2], l3 = ls[t][3];
    float m = fmaxf(fmaxf(l0, l1), fmaxf(l2, l3));
    float e0 = __expf(l0 - m), e1 = __expf(l1 - m),
          e2 = __expf(l2 - m), e3 = __expf(l3 - m);
    float inv = 1.f / (e0 + e1 + e2 + e3);
    int n = cell00 + t;
    out[n] = e0 * inv;
    out[4096 + n] = e1 * inv;
    out[8192 + n] = e2 * inv;
  }
}

extern "C" void kernel_launch(void* const* d_in, const int* in_sizes, int n_in,
                              void* d_out, int out_size, void* d_ws, size_t ws_size,
                              hipStream_t stream) {
  const float* x   = (const float*)d_in[0];
  const float* w1  = (const float*)d_in[1];
  const float* b1  = (const float*)d_in[2];
  const float* w2  = (const float*)d_in[3];
  const float* b2  = (const float*)d_in[4];
  const float* fw1 = (const float*)d_in[5];
  const float* fb1 = (const float*)d_in[6];
  const float* fw2 = (const float*)d_in[7];
  const float* fb2 = (const float*)d_in[8];
  float* out = (float*)d_out;
  ushort* fw1b = (ushort*)d_ws;   // 147456 B bf16 copy of fw1

  hipLaunchKernelGGL(prep_kernel, dim3(288), dim3(256), 0, stream, fw1, fw1b);
  hipLaunchKernelGGL(fused_kernel, dim3(512), dim3(NT), 0, stream,
                     x, w1, b1, w2, b2, fw1b, fb1, fw2, fb2, out);
}